// Round 5
// baseline (327.979 us; speedup 1.0000x reference)
//
#include <hip/hip_runtime.h>
#include <cstdint>
#include <cstddef>

typedef __bf16 bf16x8 __attribute__((ext_vector_type(8)));
typedef __bf16 bf16x4 __attribute__((ext_vector_type(4)));
typedef float f32x4 __attribute__((ext_vector_type(4)));

// ---------------------------------------------------------------------------
// Problem constants (B=1): D=2048, NH=16, DH=128, DC=512, DCQ=1024, L=2048
// ---------------------------------------------------------------------------

template <int N> __device__ __forceinline__ void waitcnt_vm() {
  if constexpr (N == 3)      asm volatile("s_waitcnt vmcnt(3)" ::: "memory");
  else if constexpr (N == 4) asm volatile("s_waitcnt vmcnt(4)" ::: "memory");
  else if constexpr (N == 6) asm volatile("s_waitcnt vmcnt(6)" ::: "memory");
  else if constexpr (N == 8) asm volatile("s_waitcnt vmcnt(8)" ::: "memory");
  else                       asm volatile("s_waitcnt vmcnt(0)" ::: "memory");
}

// ---------------------------------------------------------------------------
// MFMA GEMM core: C(M,N) = A(M,K) @ Bt(N,K)^T.  A,Bt row-major bf16.
// BM x 128 tile, BK = 32*NKS, 4 waves, double-buffered LDS + counted-vmcnt
// pipeline.  R3 post-mortem: at BK=32 the 2-barrier cost dominates (8 MFMA
// ~80cy/wave per K-step); NKS=2 doubles MFMA per barrier pair.  K-order of
// accumulation preserved (ascending 32-slices) -> bit-identical results.
//  BM=128: waves 2x2 over (128,128), wave 64x64 (acc 4x4).
//  BM=64:  waves 2x2 over (64,128),  wave 32x64 (acc 2x4).
// ---------------------------------------------------------------------------
template <int BM, int NKS, bool BF16OUT>
__device__ __forceinline__ void gemm_body(const __bf16* __restrict__ A,
                                          const __bf16* __restrict__ Bt,
                                          void* __restrict__ Cv,
                                          int N, int K, int bm, int bn,
                                          __bf16* As, __bf16* Bs) {
  const int tid = threadIdx.x;
  const int w = tid >> 6;
  const int lane = tid & 63;
  const int quad = lane >> 4;
  const int l16 = lane & 15;
  constexpr int WM = (BM == 128) ? 64 : 32;   // wave M extent
  constexpr int MI = WM / 16;                 // acc rows (4 or 2)
  constexpr int NL = NKS * (BM / 64 + 2);     // loads/wave per stage
  const int wm = (w & 1) * WM;
  const int wn = (w >> 1) * 64;
  const int srow = lane >> 2;
  const int sseg = (lane & 3) * 8;

  // stage one BK-wide K-slice into LDS buffer `buf` (async, NL loads/wave)
  auto stage = [&](int k0, int buf) {
#pragma unroll
    for (int ks = 0; ks < NKS; ++ks) {
#pragma unroll
      for (int g = 0; g < BM / 64; ++g) {     // A: BM rows
        const int grp = w + g * 4;
        const __bf16* ga = A + (size_t)(bm + grp * 16 + srow) * K + k0 + ks * 32 + sseg;
        __builtin_amdgcn_global_load_lds(
            (const __attribute__((address_space(1))) void*)ga,
            (__attribute__((address_space(3))) void*)&As[(buf * NKS + ks) * (BM * 32) + grp * 512],
            16, 0, 0);
      }
#pragma unroll
      for (int g = 0; g < 2; ++g) {           // B: always 128 rows
        const int grp = w + g * 4;
        const __bf16* gb = Bt + (size_t)(bn + grp * 16 + srow) * K + k0 + ks * 32 + sseg;
        __builtin_amdgcn_global_load_lds(
            (const __attribute__((address_space(1))) void*)gb,
            (__attribute__((address_space(3))) void*)&Bs[(buf * NKS + ks) * 4096 + grp * 512],
            16, 0, 0);
      }
    }
  };

  f32x4 acc[MI][4];
#pragma unroll
  for (int i = 0; i < MI; ++i)
#pragma unroll
    for (int j = 0; j < 4; ++j) acc[i][j] = (f32x4){0.f, 0.f, 0.f, 0.f};

  // Drain any prologue VMEM so vmcnt counts only staging traffic.
  asm volatile("s_waitcnt vmcnt(0)" ::: "memory");
  stage(0, 0);

  const int NIT = K / (32 * NKS);
  for (int it = 0; it < NIT; ++it) {
    const int cur = it & 1;
    if (it + 1 < NIT) {
      stage((it + 1) * 32 * NKS, cur ^ 1);
      waitcnt_vm<NL>();                // cur's NL loads done; next's in flight
    } else {
      waitcnt_vm<0>();
    }
    __builtin_amdgcn_s_barrier();      // all waves' cur tiles staged
    asm volatile("" ::: "memory");     // pin LDS reads below the barrier
    const __bf16* Ab = &As[cur * NKS * (BM * 32)];
    const __bf16* Bb = &Bs[cur * NKS * 4096];
#pragma unroll
    for (int ks = 0; ks < NKS; ++ks) {
      bf16x8 af[MI], bfr[4];
#pragma unroll
      for (int i = 0; i < MI; ++i)
        af[i] = *(const bf16x8*)&Ab[ks * (BM * 32) + (wm + i * 16 + l16) * 32 + quad * 8];
#pragma unroll
      for (int j = 0; j < 4; ++j)
        bfr[j] = *(const bf16x8*)&Bb[ks * 4096 + (wn + j * 16 + l16) * 32 + quad * 8];
#pragma unroll
      for (int i = 0; i < MI; ++i)
#pragma unroll
        for (int j = 0; j < 4; ++j)
          acc[i][j] = __builtin_amdgcn_mfma_f32_16x16x32_bf16(af[i], bfr[j],
                                                              acc[i][j], 0, 0, 0);
    }
    // own LDS reads done, then free buf(cur) for stage(it+2)
    asm volatile("s_waitcnt lgkmcnt(0)" ::: "memory");
    __builtin_amdgcn_s_barrier();
    asm volatile("" ::: "memory");
  }
#pragma unroll
  for (int i = 0; i < MI; ++i)
#pragma unroll
    for (int j = 0; j < 4; ++j)
#pragma unroll
      for (int r = 0; r < 4; ++r) {
        const int row = bm + wm + i * 16 + quad * 4 + r;
        const int col = bn + wn + j * 16 + l16;
        if constexpr (BF16OUT)
          ((__bf16*)Cv)[(size_t)row * N + col] = (__bf16)acc[i][j][r];
        else
          ((float*)Cv)[(size_t)row * N + col] = acc[i][j][r];
      }
}

template <int BM, int NKS, bool BF16OUT>
__global__ __launch_bounds__(256) void gemm_mfma(const __bf16* __restrict__ A,
                                                 const __bf16* __restrict__ Bt,
                                                 void* __restrict__ Cv,
                                                 int M, int N, int K) {
  __shared__ __bf16 As[2 * 128 * 32 * NKS > 2 * BM * 32 * NKS ? 2 * BM * 32 * NKS : 2 * BM * 32 * NKS];
  __shared__ __bf16 Bs[2 * 128 * 32 * NKS];
  gemm_body<BM, NKS, BF16OUT>(A, Bt, Cv, N, K, blockIdx.y * BM, blockIdx.x * 128, As, Bs);
}

// Up to 3 independent GEMMs fused by blockIdx.x ranges.
template <int BM, int NKS>
__global__ __launch_bounds__(256) void gemm_fused3(
    const __bf16* A0, const __bf16* B0, __bf16* C0, int N0, int K0, int nx0,
    const __bf16* A1, const __bf16* B1, __bf16* C1, int N1, int K1, int nx1,
    const __bf16* A2, const __bf16* B2, __bf16* C2, int N2, int K2) {
  __shared__ __bf16 As[2 * BM * 32 * NKS];
  __shared__ __bf16 Bs[2 * 128 * 32 * NKS];
  const int bx = blockIdx.x;
  const __bf16 *A, *Bt;
  __bf16* C;
  int N, K, bxl;
  if (bx < nx0)            { A = A0; Bt = B0; C = C0; N = N0; K = K0; bxl = bx; }
  else if (bx < nx0 + nx1) { A = A1; Bt = B1; C = C1; N = N1; K = K1; bxl = bx - nx0; }
  else                     { A = A2; Bt = B2; C = C2; N = N2; K = K2; bxl = bx - nx0 - nx1; }
  gemm_body<BM, NKS, true>(A, Bt, (void*)C, N, K, blockIdx.y * BM, bxl * 128, As, Bs);
}

// ---------------------------------------------------------------------------
// prep_all: all weight transposes (fp32 (K,N) -> bf16 (N,K), 32x32 tiles),
// x cast, rope tables, W_lam transpose — one launch.
// ---------------------------------------------------------------------------
__global__ __launch_bounds__(256) void prep_all(
    const float* __restrict__ W_DKV, const float* __restrict__ W_DQ,
    const float* __restrict__ W_UK,  const float* __restrict__ W_UV,
    const float* __restrict__ W_UQ,  const float* __restrict__ W_out,
    const float* __restrict__ x,     const float* __restrict__ W_lam,
    __bf16* __restrict__ tDKV, __bf16* __restrict__ tDQ,
    __bf16* __restrict__ tUK,  __bf16* __restrict__ tUV,
    __bf16* __restrict__ tUQ,  __bf16* __restrict__ tOut,
    __bf16* __restrict__ x_bf, __bf16* __restrict__ WlT,
    float* __restrict__ cosT, float* __restrict__ sinT) {
  __shared__ float T[32][36];
  int t = blockIdx.x;
  const int tid = threadIdx.x;
  if (t < 13312) {
    const float* src; __bf16* dst; int K, N, kx, ny;
    if (t < 1024)      {            src = W_DKV; dst = tDKV; K = 2048; N = 512;  kx = t & 63; ny = t >> 6; }
    else if (t < 3072) { t -= 1024; src = W_DQ;  dst = tDQ;  K = 2048; N = 1024; kx = t & 63; ny = t >> 6; }
    else if (t < 4096) { t -= 3072; src = W_UK;  dst = tUK;  K = 512;  N = 2048; kx = t & 15; ny = t >> 4; }
    else if (t < 5120) { t -= 4096; src = W_UV;  dst = tUV;  K = 512;  N = 2048; kx = t & 15; ny = t >> 4; }
    else if (t < 9216) { t -= 5120; src = W_UQ;  dst = tUQ;  K = 1024; N = 4096; kx = t & 31; ny = t >> 5; }
    else               { t -= 9216; src = W_out; dst = tOut; K = 2048; N = 2048; kx = t & 63; ny = t >> 6; }
    const int k0 = kx * 32;
    const int n0 = ny * 32;
    const int r = tid >> 3;
    const int c = (tid & 7) * 4;
    *(float4*)&T[r][c] = *(const float4*)&src[(size_t)(k0 + r) * N + n0 + c];
    __syncthreads();
    bf16x4 o = {(__bf16)T[c + 0][r], (__bf16)T[c + 1][r],
                (__bf16)T[c + 2][r], (__bf16)T[c + 3][r]};
    *(bf16x4*)&dst[(size_t)(n0 + r) * K + k0 + c] = o;
    return;
  }
  t -= 13312;
  if (t < 4096) {  // x cast: 4096 blocks x 1024 floats
    const int i = t * 256 + tid;
    float4 v = *(const float4*)&x[(size_t)i * 4];
    bf16x4 o = {(__bf16)v.x, (__bf16)v.y, (__bf16)v.z, (__bf16)v.w};
    *(bf16x4*)&x_bf[(size_t)i * 4] = o;
    return;
  }
  t -= 4096;
  if (t < 1024) {  // rope tables: 2 rows per block
    const int l = t * 2 + (tid >> 7);
    const int d = tid & 127;
    const int j = d & 63;
    const float inv = exp2f(-(float)j * 0.2076205059304601f);  // log2(1e4)/64
    const float ang = (float)l * inv;
    cosT[l * 128 + d] = cosf(ang);
    sinT[l * 128 + d] = sinf(ang);
    return;
  }
  t -= 1024;
  {  // W_lam (2048,16) -> WlT (16,2048) bf16: 128 blocks
    const int i = t * 256 + tid;
    const int k = i >> 4, n = i & 15;
    WlT[(size_t)n * 2048 + k] = (__bf16)W_lam[i];
  }
}

// ---------------------------------------------------------------------------
// ropek_transv: K-RoPE (in place) + V transpose, one launch.
// ---------------------------------------------------------------------------
__global__ __launch_bounds__(256) void ropek_transv(__bf16* __restrict__ k_bf,
                                                    const float* __restrict__ cosT,
                                                    const float* __restrict__ sinT,
                                                    const __bf16* __restrict__ v_bf,
                                                    __bf16* __restrict__ v_t) {
  __shared__ float row[2048];
  __shared__ __align__(16) __bf16 Ts[32][40];
  int t = blockIdx.x;
  const int tid = threadIdx.x;
  if (t < 2048) {  // rope row t of k_bf (W=2048)
    __bf16* rp = k_bf + (size_t)t * 2048;
#pragma unroll
    for (int i = 0; i < 2; ++i) {
      const int e4 = (tid + 256 * i) * 4;
      bf16x4 v = *(const bf16x4*)&rp[e4];
#pragma unroll
      for (int k = 0; k < 4; ++k) row[e4 + k] = (float)v[k];
    }
    __syncthreads();
#pragma unroll
    for (int i = 0; i < 8; ++i) {
      const int e = tid + 256 * i;
      const int d = e & 127;
      const float c = cosT[t * 128 + d];
      const float s = sinT[t * 128 + d];
      const float tv = row[e];
      const int base = e & ~127;
      const float rot = (d < 64) ? -row[base + d + 64] : row[base + d - 64];
      rp[e] = (__bf16)(tv * c + rot * s);
    }
    return;
  }
  t -= 2048;
  const int l0 = (t & 63) * 32;
  const int d0 = (t >> 6) * 32;
  const int r = tid >> 3;
  const int c = (tid & 7) * 4;
  *(bf16x4*)&Ts[r][c] = *(const bf16x4*)&v_bf[(size_t)(l0 + r) * 2048 + d0 + c];
  __syncthreads();
  bf16x4 o = {Ts[c + 0][r], Ts[c + 1][r], Ts[c + 2][r], Ts[c + 3][r]};
  *(bf16x4*)&v_t[(size_t)(d0 + r) * 2048 + l0 + c] = o;
}

// lam(l,h) = sigmoid(x_bf[l,:] . W_lam[:,h] + b_lam[h]) via MFMA (N=16).
__global__ __launch_bounds__(256) void lam_mfma_kernel(const __bf16* __restrict__ x_bf,
                                                       const __bf16* __restrict__ WlT,
                                                       const float* __restrict__ b_lam,
                                                       float* __restrict__ lam) {
  const int tid = threadIdx.x;
  const int w = tid >> 6, lane = tid & 63, quad = lane >> 4, l16 = lane & 15;
  const int m0 = (blockIdx.x * 4 + w) * 16;
  const __bf16* xrow = x_bf + (size_t)(m0 + l16) * 2048 + quad * 8;
  const __bf16* wrow = WlT + (size_t)l16 * 2048 + quad * 8;
  f32x4 acc[4];
#pragma unroll
  for (int u = 0; u < 4; ++u) acc[u] = (f32x4){0.f, 0.f, 0.f, 0.f};
  for (int k0 = 0; k0 < 2048; k0 += 128) {
#pragma unroll
    for (int u = 0; u < 4; ++u) {
      bf16x8 a = *(const bf16x8*)&xrow[k0 + u * 32];
      bf16x8 b = *(const bf16x8*)&wrow[k0 + u * 32];
      acc[u] = __builtin_amdgcn_mfma_f32_16x16x32_bf16(a, b, acc[u], 0, 0, 0);
    }
  }
  const float bl = b_lam[l16];
#pragma unroll
  for (int r = 0; r < 4; ++r) {
    const float v = acc[0][r] + acc[1][r] + acc[2][r] + acc[3][r] + bl;
    lam[(size_t)(m0 + quad * 4 + r) * 16 + l16] = 1.0f / (1.0f + __expf(-v));
  }
}

// ---------------------------------------------------------------------------
// Split-K schedule tables.  Chains are fixed by causality (q-tile qt needs
// qt+1 key-tiles); balanced sum-31 pairing leaves a 31-iter 1-wave/SIMD tail
// (R3 post-mortem).  Splitting qt>=16 into two key-range halves caps all
// chains at 16 and lets LPT dispatch keep 2 waves/SIMD nearly always.
// 48 slots/head, ordered by descending chain length (LPT).
// SH: 0 = unsplit, 1 = first key half, 2 = second key half.
// ---------------------------------------------------------------------------
__device__ const unsigned char SQT[48] = {
    31, 31, 30, 15,  30, 29, 29, 28, 14,  28, 27, 27, 26, 13,
    26, 25, 25, 24, 12,  24, 23, 23, 22, 11,  22, 21, 21, 20, 10,
    20, 19, 19, 18, 9,  18, 17, 17, 16, 8,  16, 7,  6, 5, 4, 3, 2, 1, 0};
__device__ const unsigned char SH[48] = {
    1, 2, 1, 0,  2, 1, 2, 1, 0,  2, 1, 2, 1, 0,
    2, 1, 2, 1, 0,  2, 1, 2, 1, 0,  2, 1, 2, 1, 0,
    2, 1, 2, 1, 0,  2, 1, 2, 1, 0,  2, 0,  0, 0, 0, 0, 0, 0, 0};

// ---------------------------------------------------------------------------
// MFMA flash attention, double-buffered K/V, counted-vmcnt pipeline, setprio.
// Grid 768 = 48 slots x 16 kv-heads.  Unsplit blocks (qt<16) write y rows
// 0..1023 directly (fused differential combine).  Split blocks (qt>=16) write
// unnormalized O + (m,l) partials in f32; attn_combine merges the two halves
// (flash merge) + differential combine for rows 1024..2047.
// LDS = 81920 B (2 blocks/CU): buf0/buf1 K 64x128 + V^T 128x64 (XOR-swizzled)
// + per-wave P 32x64.
// ---------------------------------------------------------------------------
__global__ __launch_bounds__(256, 2) void attn_kernel3(
    const __bf16* __restrict__ Qb, const __bf16* __restrict__ Kb,
    const __bf16* __restrict__ Vt, const float* __restrict__ cosT,
    const float* __restrict__ sinT, const float* __restrict__ lam,
    __bf16* __restrict__ y, float* __restrict__ Opart,
    float* __restrict__ Mlp) {
  __shared__ __align__(16) char smem[81920];
  float (*Ex)[132] = (float(*)[132])smem;              // epilogue union (33.8 KB)

  const int bx = blockIdx.x;
  const int slot = bx >> 4;
  const int hk = bx & 15;
  const int qt = SQT[slot];
  const int hf = SH[slot];                   // 0 unsplit, 1 lo-half, 2 hi-half
  const int q0 = qt * 64;
  const int half = (qt + 2) >> 1;            // ceil((qt+1)/2)
  const int kt_lo = (hf == 2) ? half : 0;
  const int kt_hi = (hf == 1) ? half : qt + 1;
  const int tid = threadIdx.x;
  const int w = tid >> 6, lane = tid & 63, quad = lane >> 4, l16 = lane & 15;
  const int wrow = (w & 1) * 32;
  const int qoff = (2 * hk + (w >> 1)) * 128;
  const int kvoff = hk * 128;
  const float qscale = 0.08838834764831845f;  // 1/sqrt(128), folded into Q
  char* Pw = smem + 65536 + w * (32 * 128);   // 32 rows x 128 B per wave

  // ---- Q fragments + RoPE + scale in-register ----
  bf16x8 aq[2][4];
#pragma unroll
  for (int s = 0; s < 2; ++s) {
    const int l = q0 + wrow + s * 16 + l16;
    const size_t qbase = (size_t)l * 4096 + qoff + quad * 8;
    bf16x8 raw[4];
#pragma unroll
    for (int ks = 0; ks < 4; ++ks)
      raw[ks] = *(const bf16x8*)&Qb[qbase + ks * 32];
#pragma unroll
    for (int ks = 0; ks < 4; ++ks) {
      const float* cp = &cosT[l * 128 + ks * 32 + quad * 8];
      const float* sp = &sinT[l * 128 + ks * 32 + quad * 8];
#pragma unroll
      for (int j = 0; j < 8; ++j) {
        const float cv = cp[j];
        const float sv = sp[j];
        const float rot = (ks < 2) ? -(float)raw[ks + 2][j] : (float)raw[ks - 2][j];
        aq[s][ks][j] = (__bf16)(((float)raw[ks][j] * cv + rot * sv) * qscale);
      }
    }
  }

  // ---- staging helper: 8 global_load_lds per wave into chosen buffer ----
  auto stage = [&](int kt_, char* buf) {
    const int k0_ = kt_ * 64;
    __bf16* Ksb = (__bf16*)buf;
    __bf16* Vsb = (__bf16*)(buf + 16384);
#pragma unroll
    for (int d = 0; d < 4; ++d) {
      const int r0 = w * 16 + d * 4;             // 4 K-rows per DMA
      const int row = r0 + (lane >> 4);
      const int ck = (lane & 15) ^ (row & 15);
      const __bf16* ga = Kb + (size_t)(k0_ + row) * 2048 + kvoff + ck * 8;
      __builtin_amdgcn_global_load_lds(
          (const __attribute__((address_space(1))) void*)ga,
          (__attribute__((address_space(3))) void*)&Ksb[r0 * 128], 16, 0, 0);
      const int r0v = w * 32 + d * 8;            // 8 V-rows per DMA
      const int rowv = r0v + (lane >> 3);
      const int cv = (lane & 7) ^ (rowv & 7);
      const __bf16* gv = Vt + (size_t)(kvoff + rowv) * 2048 + k0_ + cv * 8;
      __builtin_amdgcn_global_load_lds(
          (const __attribute__((address_space(1))) void*)gv,
          (__attribute__((address_space(3))) void*)&Vsb[r0v * 64], 16, 0, 0);
    }
  };

  f32x4 o[2][8];
#pragma unroll
  for (int s = 0; s < 2; ++s)
#pragma unroll
    for (int i = 0; i < 8; ++i) o[s][i] = (f32x4){0.f, 0.f, 0.f, 0.f};
  float m[2] = {-1e30f, -1e30f}, lsum[2] = {0.f, 0.f};

  // Drain Q/rope loads so vmcnt counts only staging traffic, then prologue.
  asm volatile("s_waitcnt vmcnt(0)" ::: "memory");
  stage(kt_lo, smem);

  for (int kt = kt_lo; kt < kt_hi; ++kt) {
    const int cur = (kt - kt_lo) & 1;
    __bf16* Ks = (__bf16*)(smem + cur * 32768);
    __bf16* Vs = (__bf16*)(smem + cur * 32768 + 16384);
    const int k0 = kt * 64;
    if (kt + 1 < kt_hi) {
      stage(kt + 1, smem + (cur ^ 1) * 32768);
      asm volatile("s_waitcnt vmcnt(8)" ::: "memory");  // kt's 8 loads done
    } else {
      asm volatile("s_waitcnt vmcnt(0)" ::: "memory");
    }
    __builtin_amdgcn_s_barrier();        // all waves' kt tiles staged
    asm volatile("" ::: "memory");       // pin LDS reads below the barrier
    // ---- S^T = K Q^T : 4 key m-tiles x 4 k-steps x 2 q-subtiles ----
    f32x4 st[2][4];
#pragma unroll
    for (int s = 0; s < 2; ++s)
#pragma unroll
      for (int t = 0; t < 4; ++t) st[s][t] = (f32x4){0.f, 0.f, 0.f, 0.f};
    __builtin_amdgcn_s_setprio(1);
#pragma unroll
    for (int ks = 0; ks < 4; ++ks) {
#pragma unroll
      for (int t = 0; t < 4; ++t) {
        bf16x8 ak = *(bf16x8*)&Ks[(t * 16 + l16) * 128 + (((ks * 4 + quad) ^ l16) << 3)];
        st[0][t] = __builtin_amdgcn_mfma_f32_16x16x32_bf16(ak, aq[0][ks], st[0][t], 0, 0, 0);
        st[1][t] = __builtin_amdgcn_mfma_f32_16x16x32_bf16(ak, aq[1][ks], st[1][t], 0, 0, 0);
      }
    }
    __builtin_amdgcn_s_setprio(0);
    // ---- online softmax (scale pre-folded into Q) ----
    const bool masked = (kt == qt);
#pragma unroll
    for (int s = 0; s < 2; ++s) {
      const int q = q0 + wrow + s * 16 + l16;
      float rm = -1e30f;
      if (!masked) {
#pragma unroll
        for (int t = 0; t < 4; ++t)
#pragma unroll
          for (int r = 0; r < 4; ++r) rm = fmaxf(rm, st[s][t][r]);
      } else {
#pragma unroll
        for (int t = 0; t < 4; ++t)
#pragma unroll
          for (int r = 0; r < 4; ++r) {
            const int key = k0 + t * 16 + quad * 4 + r;
            if (key > q) st[s][t][r] = -1e30f;
            rm = fmaxf(rm, st[s][t][r]);
          }
      }
      rm = fmaxf(rm, __shfl_xor(rm, 16, 64));
      rm = fmaxf(rm, __shfl_xor(rm, 32, 64));
      const float mn = fmaxf(m[s], rm);
      const float alpha = __expf(m[s] - mn);
      float rs = 0.f;
#pragma unroll
      for (int t = 0; t < 4; ++t)
#pragma unroll
        for (int r = 0; r < 4; ++r) {
          st[s][t][r] = __expf(st[s][t][r] - mn);
          rs += st[s][t][r];
        }
      rs += __shfl_xor(rs, 16, 64);
      rs += __shfl_xor(rs, 32, 64);
      m[s] = mn;
      lsum[s] = lsum[s] * alpha + rs;
      const int prow = s * 16 + l16;
#pragma unroll
      for (int t = 0; t < 4; ++t) {
        bf16x4 pk = {(__bf16)st[s][t][0], (__bf16)st[s][t][1],
                     (__bf16)st[s][t][2], (__bf16)st[s][t][3]};
        const int wch = (t * 2 + (quad >> 1)) ^ (prow & 7);  // 16B-chunk swizzle
        *(bf16x4*)(Pw + prow * 128 + wch * 16 + (quad & 1) * 8) = pk;
      }
#pragma unroll
      for (int r = 0; r < 4; ++r) {
        const float ar = __shfl(alpha, quad * 4 + r, 64);
#pragma unroll
        for (int nt = 0; nt < 8; ++nt) o[s][nt][r] *= ar;
      }
    }
    // ---- O += P V : per-wave P (no barrier), each bv feeds 2 MFMAs ----
    __builtin_amdgcn_s_setprio(1);
#pragma unroll
    for (int ks = 0; ks < 2; ++ks) {
      const int rch = ((ks * 4 + quad) ^ (l16 & 7)) << 4;   // swizzled 16B chunk
      bf16x8 pa0 = *(bf16x8*)(Pw + l16 * 128 + rch);
      bf16x8 pa1 = *(bf16x8*)(Pw + (16 + l16) * 128 + rch);
#pragma unroll
      for (int nt = 0; nt < 8; ++nt) {
        bf16x8 bv = *(bf16x8*)&Vs[(nt * 16 + l16) * 64 + (((ks * 4 + quad) ^ (l16 & 7)) << 3)];
        o[0][nt] = __builtin_amdgcn_mfma_f32_16x16x32_bf16(pa0, bv, o[0][nt], 0, 0, 0);
        o[1][nt] = __builtin_amdgcn_mfma_f32_16x16x32_bf16(pa1, bv, o[1][nt], 0, 0, 0);
      }
    }
    __builtin_amdgcn_s_setprio(0);
    // ---- end-of-tile: own LDS reads done, then free buf(kt^1) ----
    asm volatile("s_waitcnt lgkmcnt(0)" ::: "memory");
    __builtin_amdgcn_s_barrier();
    asm volatile("" ::: "memory");
  }
  if (hf == 0) {
    // ---- fused differential combine (unsplit): y rows q0..q0+63 ----
    if (w >= 2) {   // q-head 2hk+1: publish inv-scaled O
#pragma unroll
      for (int s = 0; s < 2; ++s) {
        const float linv = 1.0f / lsum[s];
#pragma unroll
        for (int r = 0; r < 4; ++r) {
          const float inv = __shfl(linv, quad * 4 + r, 64);
          const int rr = wrow + s * 16 + quad * 4 + r;
#pragma unroll
          for (int nt = 0; nt < 8; ++nt)
            Ex[rr][nt * 16 + l16] = o[s][nt][r] * inv;
        }
      }
    }
    __syncthreads();
    if (w < 2) {    // q-head 2hk: combine and write y
#pragma unroll
      for (int s = 0; s < 2; ++s) {
        const float linv = 1.0f / lsum[s];
#pragma unroll
        for (int r = 0; r < 4; ++r) {
          const float inv = __shfl(linv, quad * 4 + r, 64);
          const int rr = wrow + s * 16 + quad * 4 + r;
          const int l = q0 + rr;
          const float lm = lam[l * 16 + hk];
          __bf16* dst = y + (size_t)l * 2048 + hk * 128;
#pragma unroll
          for (int nt = 0; nt < 8; ++nt) {
            const float v1 = o[s][nt][r] * inv;
            dst[nt * 16 + l16] = (__bf16)(v1 - lm * Ex[rr][nt * 16 + l16]);
          }
        }
      }
    }
  } else {
    // ---- split: write unnormalized O + (m,l) partials (per-wave data) ----
    const int ti = (((qt - 16) * 16 + hk) * 2 + (w >> 1)) * 2 + (hf - 1);
    float* Ob = Opart + (size_t)ti * 8192;
#pragma unroll
    for (int s = 0; s < 2; ++s) {
      if (lane < 16)
        *(float2*)&Mlp[(size_t)ti * 128 + (wrow + s * 16 + l16) * 2] =
            (float2){m[s], lsum[s]};
#pragma unroll
      for (int r = 0; r < 4; ++r) {
        const int rr = wrow + s * 16 + quad * 4 + r;
#pragma unroll
        for (int nt = 0; nt < 8; ++nt)
          Ob[rr * 128 + nt * 16 + l16] = o[s][nt][r];
      }
    }
  }
}

// ---------------------------------------------------------------------------
// attn_combine: flash-merge the two key halves + differential combine.
// Covers y rows 1024..2047.  Grid 1024 = 16 qt x 16 hk x 4 row-quarters.
// ---------------------------------------------------------------------------
__global__ __launch_bounds__(256) void attn_combine(
    const float* __restrict__ Op, const float* __restrict__ Ml,
    const float* __restrict__ lam, __bf16* __restrict__ y) {
  const int b = blockIdx.x;
  const int qt16 = b >> 6;
  const int hk = (b >> 2) & 15;
  const int r0 = (b & 3) * 16;
  const int tid = threadIdx.x;
  const int d = tid & 127;
  const int rbase = r0 + (tid >> 7);
  const int tb = (qt16 * 16 + hk) * 4;
#pragma unroll
  for (int k = 0; k < 8; ++k) {
    const int rr = rbase + k * 2;
    const int l = (qt16 + 16) * 64 + rr;
    float Oh[2];
#pragma unroll
    for (int h01 = 0; h01 < 2; ++h01) {
      const int t1 = tb + h01 * 2, t2 = t1 + 1;
      const float m1 = Ml[t1 * 128 + rr * 2], l1 = Ml[t1 * 128 + rr * 2 + 1];
      const float m2 = Ml[t2 * 128 + rr * 2], l2 = Ml[t2 * 128 + rr * 2 + 1];
      const float mm = fmaxf(m1, m2);
      const float a1 = __expf(m1 - mm), a2 = __expf(m2 - mm);
      const float inv = 1.0f / (l1 * a1 + l2 * a2);
      Oh[h01] = (a1 * Op[(size_t)t1 * 8192 + rr * 128 + d] +
                 a2 * Op[(size_t)t2 * 8192 + rr * 128 + d]) * inv;
    }
    const float lm = lam[(size_t)l * 16 + hk];
    y[(size_t)l * 2048 + hk * 128 + d] = (__bf16)(Oh[0] - lm * Oh[1]);
  }
}

extern "C" void kernel_launch(void* const* d_in, const int* in_sizes, int n_in,
                              void* d_out, int out_size, void* d_ws, size_t ws_size,
                              hipStream_t stream) {
  const float* x     = (const float*)d_in[0];
  const float* W_DKV = (const float*)d_in[1];
  const float* W_UK  = (const float*)d_in[2];
  const float* W_UV  = (const float*)d_in[3];
  const float* W_DQ  = (const float*)d_in[4];
  const float* W_UQ  = (const float*)d_in[5];
  const float* W_lam = (const float*)d_in[6];
  const float* b_lam = (const float*)d_in[7];
  const float* W_out = (const float*)d_in[8];
  float* out = (float*)d_out;

  char* ws = (char*)d_ws;
  #define MB(n) ((size_t)(n) << 20)
  __bf16* x_bf   = (__bf16*)(ws + MB(0));    //  8 MB (2048x2048)
  __bf16* Wt_DKV = (__bf16*)(ws + MB(8));    //  2 MB (512x2048)
  __bf16* Wt_DQ  = (__bf16*)(ws + MB(10));   //  4 MB (1024x2048)
  __bf16* c_kv   = (__bf16*)(ws + MB(14));   //  2 MB (2048x512)
  __bf16* c_q    = (__bf16*)(ws + MB(16));   //  4 MB (2048x1024)
  __bf16* Wt_UK  = (__bf16*)(ws + MB(20));   //  2 MB (2048x512)
  __bf16* Wt_UV  = (__bf16*)(ws + MB(22));   //  2 MB (2048x512)
  __bf16* Wt_UQ  = (__bf16*)(ws + MB(24));   //  8 MB (4096x1024)
  __bf16* k_bf   = (__bf16*)(ws + MB(32));   //  8 MB (2048x2048)
  __bf16* v_bf   = (__bf16*)(ws + MB(40));   //  8 MB (2048x2048)
  __bf16* y_bf   = (__bf16*)(ws + MB(40));   //  8 MB alias: v_bf dead after v_t
  __bf16* q_bf   = (__bf16*)(ws + MB(48));   // 16 MB (2048x4096) un-roped
  __bf16* v_t    = (__bf16*)(ws + MB(64));   //  8 MB (2048x2048)
  float*  lam    = (float*)(ws + MB(88));    // 128 KB
  float*  cosT   = (float*)(ws + MB(89));    //  1 MB
  float*  sinT   = (float*)(ws + MB(90));    //  1 MB
  __bf16* WlT    = (__bf16*)(ws + MB(91));   // 64 KB (16x2048)
  __bf16* Wt_out = (__bf16*)(ws + MB(92));   //  8 MB (2048x2048)  (total 100 MB)
  // Attn split-K partials: MB(0..32) is dead by attn time (x_bf/Wt_*/c_* all
  // consumed).  Opart = 1024 tiles x 64x128 f32 = exactly 32 MiB.
  float*  Opart  = (float*)(ws + MB(0));
  float*  Mlp    = (float*)(ws + MB(88) + 131072);   // 512 KB, after lam

  // one prep launch: 6 weight transposes + x cast + rope tables + W_lam^T
  prep_all<<<18560, 256, 0, stream>>>(W_DKV, W_DQ, W_UK, W_UV, W_UQ, W_out,
                                      x, W_lam,
                                      Wt_DKV, Wt_DQ, Wt_UK, Wt_UV, Wt_UQ, Wt_out,
                                      x_bf, WlT, cosT, sinT);
  // fused down-projections, BM=64 BK=64 (384 blocks): DKV (4) + DQ (8)
  gemm_fused3<64, 2><<<dim3(12, 32), 256, 0, stream>>>(
      x_bf, Wt_DKV, c_kv, 512, 2048, 4,
      x_bf, Wt_DQ,  c_q, 1024, 2048, 8,
      x_bf, Wt_DQ,  c_q, 1024, 2048);
  lam_mfma_kernel<<<32, 256, 0, stream>>>(x_bf, WlT, b_lam, lam);
  // fused up-projections: UK (16) + UV (16) + UQ (32) — BM=128 BK=32 (4/CU)
  gemm_fused3<128, 1><<<dim3(64, 16), 256, 0, stream>>>(
      c_kv, Wt_UK, k_bf, 2048, 512, 16,
      c_kv, Wt_UV, v_bf, 2048, 512, 16,
      c_q,  Wt_UQ, q_bf, 4096, 1024);
  // K-RoPE + V transpose, one launch
  ropek_transv<<<6144, 256, 0, stream>>>(k_bf, cosT, sinT, v_bf, v_t);
  // flash attention: split-K balanced (768 blocks, LPT slot order) -> y_bf
  attn_kernel3<<<768, 256, 0, stream>>>(q_bf, k_bf, v_t, cosT, sinT, lam, y_bf,
                                        Opart, Mlp);
  // merge split halves + differential combine for rows 1024..2047
  attn_combine<<<1024, 256, 0, stream>>>(Opart, Mlp, lam, y_bf);
  // output projection, BM=64 BK=64 (512 blocks = 2/CU)
  gemm_mfma<64, 2, false><<<dim3(16, 32), 256, 0, stream>>>(y_bf, Wt_out, out, 2048, 2048, 2048);
}

// Round 6
// 306.084 us; speedup vs baseline: 1.0715x; 1.0715x over previous
//
#include <hip/hip_runtime.h>
#include <cstdint>
#include <cstddef>

typedef __bf16 bf16x8 __attribute__((ext_vector_type(8)));
typedef __bf16 bf16x4 __attribute__((ext_vector_type(4)));
typedef float f32x4 __attribute__((ext_vector_type(4)));

// ---------------------------------------------------------------------------
// Problem constants (B=1): D=2048, NH=16, DH=128, DC=512, DCQ=1024, L=2048
// ---------------------------------------------------------------------------

template <int N> __device__ __forceinline__ void waitcnt_vm() {
  if constexpr (N == 3)      asm volatile("s_waitcnt vmcnt(3)" ::: "memory");
  else if constexpr (N == 4) asm volatile("s_waitcnt vmcnt(4)" ::: "memory");
  else if constexpr (N == 6) asm volatile("s_waitcnt vmcnt(6)" ::: "memory");
  else if constexpr (N == 8) asm volatile("s_waitcnt vmcnt(8)" ::: "memory");
  else                       asm volatile("s_waitcnt vmcnt(0)" ::: "memory");
}

// ---------------------------------------------------------------------------
// MFMA GEMM core: C(M,N) = A(M,K) @ Bt(N,K)^T.  A,Bt row-major bf16.
// BM x 128 tile, BK = 32*NKS, 4 waves, double-buffered LDS + counted-vmcnt
// pipeline.  K-order of accumulation preserved -> bit-identical results.
//  BM=128: waves 2x2 over (128,128), wave 64x64 (acc 4x4).
//  BM=64:  waves 2x2 over (64,128),  wave 32x64 (acc 2x4).
// ---------------------------------------------------------------------------
template <int BM, int NKS, bool BF16OUT>
__device__ __forceinline__ void gemm_body(const __bf16* __restrict__ A,
                                          const __bf16* __restrict__ Bt,
                                          void* __restrict__ Cv,
                                          int N, int K, int bm, int bn,
                                          __bf16* As, __bf16* Bs) {
  const int tid = threadIdx.x;
  const int w = tid >> 6;
  const int lane = tid & 63;
  const int quad = lane >> 4;
  const int l16 = lane & 15;
  constexpr int WM = (BM == 128) ? 64 : 32;   // wave M extent
  constexpr int MI = WM / 16;                 // acc rows (4 or 2)
  constexpr int NL = NKS * (BM / 64 + 2);     // loads/wave per stage
  const int wm = (w & 1) * WM;
  const int wn = (w >> 1) * 64;
  const int srow = lane >> 2;
  const int sseg = (lane & 3) * 8;

  // stage one BK-wide K-slice into LDS buffer `buf` (async, NL loads/wave)
  auto stage = [&](int k0, int buf) {
#pragma unroll
    for (int ks = 0; ks < NKS; ++ks) {
#pragma unroll
      for (int g = 0; g < BM / 64; ++g) {     // A: BM rows
        const int grp = w + g * 4;
        const __bf16* ga = A + (size_t)(bm + grp * 16 + srow) * K + k0 + ks * 32 + sseg;
        __builtin_amdgcn_global_load_lds(
            (const __attribute__((address_space(1))) void*)ga,
            (__attribute__((address_space(3))) void*)&As[(buf * NKS + ks) * (BM * 32) + grp * 512],
            16, 0, 0);
      }
#pragma unroll
      for (int g = 0; g < 2; ++g) {           // B: always 128 rows
        const int grp = w + g * 4;
        const __bf16* gb = Bt + (size_t)(bn + grp * 16 + srow) * K + k0 + ks * 32 + sseg;
        __builtin_amdgcn_global_load_lds(
            (const __attribute__((address_space(1))) void*)gb,
            (__attribute__((address_space(3))) void*)&Bs[(buf * NKS + ks) * 4096 + grp * 512],
            16, 0, 0);
      }
    }
  };

  f32x4 acc[MI][4];
#pragma unroll
  for (int i = 0; i < MI; ++i)
#pragma unroll
    for (int j = 0; j < 4; ++j) acc[i][j] = (f32x4){0.f, 0.f, 0.f, 0.f};

  // Drain any prologue VMEM so vmcnt counts only staging traffic.
  asm volatile("s_waitcnt vmcnt(0)" ::: "memory");
  stage(0, 0);

  const int NIT = K / (32 * NKS);
  for (int it = 0; it < NIT; ++it) {
    const int cur = it & 1;
    if (it + 1 < NIT) {
      stage((it + 1) * 32 * NKS, cur ^ 1);
      waitcnt_vm<NL>();                // cur's NL loads done; next's in flight
    } else {
      waitcnt_vm<0>();
    }
    __builtin_amdgcn_s_barrier();      // all waves' cur tiles staged
    asm volatile("" ::: "memory");     // pin LDS reads below the barrier
    const __bf16* Ab = &As[cur * NKS * (BM * 32)];
    const __bf16* Bb = &Bs[cur * NKS * 4096];
#pragma unroll
    for (int ks = 0; ks < NKS; ++ks) {
      bf16x8 af[MI], bfr[4];
#pragma unroll
      for (int i = 0; i < MI; ++i)
        af[i] = *(const bf16x8*)&Ab[ks * (BM * 32) + (wm + i * 16 + l16) * 32 + quad * 8];
#pragma unroll
      for (int j = 0; j < 4; ++j)
        bfr[j] = *(const bf16x8*)&Bb[ks * 4096 + (wn + j * 16 + l16) * 32 + quad * 8];
#pragma unroll
      for (int i = 0; i < MI; ++i)
#pragma unroll
        for (int j = 0; j < 4; ++j)
          acc[i][j] = __builtin_amdgcn_mfma_f32_16x16x32_bf16(af[i], bfr[j],
                                                              acc[i][j], 0, 0, 0);
    }
    // own LDS reads done, then free buf(cur) for stage(it+2)
    asm volatile("s_waitcnt lgkmcnt(0)" ::: "memory");
    __builtin_amdgcn_s_barrier();
    asm volatile("" ::: "memory");
  }
#pragma unroll
  for (int i = 0; i < MI; ++i)
#pragma unroll
    for (int j = 0; j < 4; ++j)
#pragma unroll
      for (int r = 0; r < 4; ++r) {
        const int row = bm + wm + i * 16 + quad * 4 + r;
        const int col = bn + wn + j * 16 + l16;
        if constexpr (BF16OUT)
          ((__bf16*)Cv)[(size_t)row * N + col] = (__bf16)acc[i][j][r];
        else
          ((float*)Cv)[(size_t)row * N + col] = acc[i][j][r];
      }
}

template <int BM, int NKS, bool BF16OUT>
__global__ __launch_bounds__(256) void gemm_mfma(const __bf16* __restrict__ A,
                                                 const __bf16* __restrict__ Bt,
                                                 void* __restrict__ Cv,
                                                 int M, int N, int K) {
  __shared__ __bf16 As[2 * BM * 32 * NKS];
  __shared__ __bf16 Bs[2 * 128 * 32 * NKS];
  gemm_body<BM, NKS, BF16OUT>(A, Bt, Cv, N, K, blockIdx.y * BM, blockIdx.x * 128, As, Bs);
}

// Up to 3 independent GEMMs fused by blockIdx.x ranges.
template <int BM, int NKS>
__global__ __launch_bounds__(256) void gemm_fused3(
    const __bf16* A0, const __bf16* B0, __bf16* C0, int N0, int K0, int nx0,
    const __bf16* A1, const __bf16* B1, __bf16* C1, int N1, int K1, int nx1,
    const __bf16* A2, const __bf16* B2, __bf16* C2, int N2, int K2) {
  __shared__ __bf16 As[2 * BM * 32 * NKS];
  __shared__ __bf16 Bs[2 * 128 * 32 * NKS];
  const int bx = blockIdx.x;
  const __bf16 *A, *Bt;
  __bf16* C;
  int N, K, bxl;
  if (bx < nx0)            { A = A0; Bt = B0; C = C0; N = N0; K = K0; bxl = bx; }
  else if (bx < nx0 + nx1) { A = A1; Bt = B1; C = C1; N = N1; K = K1; bxl = bx - nx0; }
  else                     { A = A2; Bt = B2; C = C2; N = N2; K = K2; bxl = bx - nx0 - nx1; }
  gemm_body<BM, NKS, true>(A, Bt, (void*)C, N, K, blockIdx.y * BM, bxl * 128, As, Bs);
}

// ---------------------------------------------------------------------------
// prep_all: all weight transposes (fp32 (K,N) -> bf16 (N,K), 32x32 tiles),
// x cast, rope tables, W_lam transpose — one launch.
// ---------------------------------------------------------------------------
__global__ __launch_bounds__(256) void prep_all(
    const float* __restrict__ W_DKV, const float* __restrict__ W_DQ,
    const float* __restrict__ W_UK,  const float* __restrict__ W_UV,
    const float* __restrict__ W_UQ,  const float* __restrict__ W_out,
    const float* __restrict__ x,     const float* __restrict__ W_lam,
    __bf16* __restrict__ tDKV, __bf16* __restrict__ tDQ,
    __bf16* __restrict__ tUK,  __bf16* __restrict__ tUV,
    __bf16* __restrict__ tUQ,  __bf16* __restrict__ tOut,
    __bf16* __restrict__ x_bf, __bf16* __restrict__ WlT,
    float* __restrict__ cosT, float* __restrict__ sinT) {
  __shared__ float T[32][36];
  int t = blockIdx.x;
  const int tid = threadIdx.x;
  if (t < 13312) {
    const float* src; __bf16* dst; int K, N, kx, ny;
    if (t < 1024)      {            src = W_DKV; dst = tDKV; K = 2048; N = 512;  kx = t & 63; ny = t >> 6; }
    else if (t < 3072) { t -= 1024; src = W_DQ;  dst = tDQ;  K = 2048; N = 1024; kx = t & 63; ny = t >> 6; }
    else if (t < 4096) { t -= 3072; src = W_UK;  dst = tUK;  K = 512;  N = 2048; kx = t & 15; ny = t >> 4; }
    else if (t < 5120) { t -= 4096; src = W_UV;  dst = tUV;  K = 512;  N = 2048; kx = t & 15; ny = t >> 4; }
    else if (t < 9216) { t -= 5120; src = W_UQ;  dst = tUQ;  K = 1024; N = 4096; kx = t & 31; ny = t >> 5; }
    else               { t -= 9216; src = W_out; dst = tOut; K = 2048; N = 2048; kx = t & 63; ny = t >> 6; }
    const int k0 = kx * 32;
    const int n0 = ny * 32;
    const int r = tid >> 3;
    const int c = (tid & 7) * 4;
    *(float4*)&T[r][c] = *(const float4*)&src[(size_t)(k0 + r) * N + n0 + c];
    __syncthreads();
    bf16x4 o = {(__bf16)T[c + 0][r], (__bf16)T[c + 1][r],
                (__bf16)T[c + 2][r], (__bf16)T[c + 3][r]};
    *(bf16x4*)&dst[(size_t)(n0 + r) * K + k0 + c] = o;
    return;
  }
  t -= 13312;
  if (t < 4096) {  // x cast: 4096 blocks x 1024 floats
    const int i = t * 256 + tid;
    float4 v = *(const float4*)&x[(size_t)i * 4];
    bf16x4 o = {(__bf16)v.x, (__bf16)v.y, (__bf16)v.z, (__bf16)v.w};
    *(bf16x4*)&x_bf[(size_t)i * 4] = o;
    return;
  }
  t -= 4096;
  if (t < 1024) {  // rope tables: 2 rows per block
    const int l = t * 2 + (tid >> 7);
    const int d = tid & 127;
    const int j = d & 63;
    const float inv = exp2f(-(float)j * 0.2076205059304601f);  // log2(1e4)/64
    const float ang = (float)l * inv;
    cosT[l * 128 + d] = cosf(ang);
    sinT[l * 128 + d] = sinf(ang);
    return;
  }
  t -= 1024;
  {  // W_lam (2048,16) -> WlT (16,2048) bf16: 128 blocks
    const int i = t * 256 + tid;
    const int k = i >> 4, n = i & 15;
    WlT[(size_t)n * 2048 + k] = (__bf16)W_lam[i];
  }
}

// ---------------------------------------------------------------------------
// ropek_transv: K-RoPE (in place) + V transpose, one launch.
// ---------------------------------------------------------------------------
__global__ __launch_bounds__(256) void ropek_transv(__bf16* __restrict__ k_bf,
                                                    const float* __restrict__ cosT,
                                                    const float* __restrict__ sinT,
                                                    const __bf16* __restrict__ v_bf,
                                                    __bf16* __restrict__ v_t) {
  __shared__ float row[2048];
  __shared__ __align__(16) __bf16 Ts[32][40];
  int t = blockIdx.x;
  const int tid = threadIdx.x;
  if (t < 2048) {  // rope row t of k_bf (W=2048)
    __bf16* rp = k_bf + (size_t)t * 2048;
#pragma unroll
    for (int i = 0; i < 2; ++i) {
      const int e4 = (tid + 256 * i) * 4;
      bf16x4 v = *(const bf16x4*)&rp[e4];
#pragma unroll
      for (int k = 0; k < 4; ++k) row[e4 + k] = (float)v[k];
    }
    __syncthreads();
#pragma unroll
    for (int i = 0; i < 8; ++i) {
      const int e = tid + 256 * i;
      const int d = e & 127;
      const float c = cosT[t * 128 + d];
      const float s = sinT[t * 128 + d];
      const float tv = row[e];
      const int base = e & ~127;
      const float rot = (d < 64) ? -row[base + d + 64] : row[base + d - 64];
      rp[e] = (__bf16)(tv * c + rot * s);
    }
    return;
  }
  t -= 2048;
  const int l0 = (t & 63) * 32;
  const int d0 = (t >> 6) * 32;
  const int r = tid >> 3;
  const int c = (tid & 7) * 4;
  *(bf16x4*)&Ts[r][c] = *(const bf16x4*)&v_bf[(size_t)(l0 + r) * 2048 + d0 + c];
  __syncthreads();
  bf16x4 o = {Ts[c + 0][r], Ts[c + 1][r], Ts[c + 2][r], Ts[c + 3][r]};
  *(bf16x4*)&v_t[(size_t)(d0 + r) * 2048 + l0 + c] = o;
}

// lam(l,h) = sigmoid(x_bf[l,:] . W_lam[:,h] + b_lam[h]) via MFMA (N=16).
__global__ __launch_bounds__(256) void lam_mfma_kernel(const __bf16* __restrict__ x_bf,
                                                       const __bf16* __restrict__ WlT,
                                                       const float* __restrict__ b_lam,
                                                       float* __restrict__ lam) {
  const int tid = threadIdx.x;
  const int w = tid >> 6, lane = tid & 63, quad = lane >> 4, l16 = lane & 15;
  const int m0 = (blockIdx.x * 4 + w) * 16;
  const __bf16* xrow = x_bf + (size_t)(m0 + l16) * 2048 + quad * 8;
  const __bf16* wrow = WlT + (size_t)l16 * 2048 + quad * 8;
  f32x4 acc[4];
#pragma unroll
  for (int u = 0; u < 4; ++u) acc[u] = (f32x4){0.f, 0.f, 0.f, 0.f};
  for (int k0 = 0; k0 < 2048; k0 += 128) {
#pragma unroll
    for (int u = 0; u < 4; ++u) {
      bf16x8 a = *(const bf16x8*)&xrow[k0 + u * 32];
      bf16x8 b = *(const bf16x8*)&wrow[k0 + u * 32];
      acc[u] = __builtin_amdgcn_mfma_f32_16x16x32_bf16(a, b, acc[u], 0, 0, 0);
    }
  }
  const float bl = b_lam[l16];
#pragma unroll
  for (int r = 0; r < 4; ++r) {
    const float v = acc[0][r] + acc[1][r] + acc[2][r] + acc[3][r] + bl;
    lam[(size_t)(m0 + quad * 4 + r) * 16 + l16] = 1.0f / (1.0f + __expf(-v));
  }
}

// ---------------------------------------------------------------------------
// MFMA flash attention, 512-thread blocks (8 waves), double-buffered K/V,
// counted-vmcnt pipeline + setprio.  R4 post-mortem: split-K partial round
// trip cost > tail savings; R5 instead halves per-wave work and doubles
// waves: wave w (0..7) owns 16 q-rows of head (w>>2) — 16 waves/CU = 4/SIMD
// in pair regime, 2/SIMD in the tail (was 1).  Same arithmetic per row,
// same accumulation order -> bit-identical.  Exact defer-rescale: when the
// running max didn't grow, alpha == exp(0) == 1 -> skip is bit-identical.
//  Block = (kv-head hk, 64 q-rows).  Grid 512, pairs (31-k, k) per CU.
//  LDS = 81920 B (2 blocks/CU):
//    [0,32K)   buf0: Ks 64x128 (16K) + Vs^T 128x64 (16K), XOR-swizzled
//    [32K,64K) buf1: same
//    [64K,80K) P: per-wave 16 rows x 64 keys bf16 (2 KB each)
// ---------------------------------------------------------------------------
__global__ __launch_bounds__(512, 2) void attn_kernel3(
    const __bf16* __restrict__ Qb, const __bf16* __restrict__ Kb,
    const __bf16* __restrict__ Vt, const float* __restrict__ cosT,
    const float* __restrict__ sinT, const float* __restrict__ lam,
    __bf16* __restrict__ y) {
  __shared__ __align__(16) char smem[81920];
  float (*Ex)[132] = (float(*)[132])smem;              // epilogue union (33.8 KB)

  const int bx = blockIdx.x;
  const int hv = bx >> 8;
  const int ii = bx & 255;
  const int qt = hv ? (ii >> 4) : 31 - (ii >> 4);  // pairs (31-k, k) per CU
  const int hk = ii & 15;
  const int q0 = qt * 64;
  const int tid = threadIdx.x;
  const int w = tid >> 6, lane = tid & 63, quad = lane >> 4, l16 = lane & 15;
  const int wrow = (w & 3) * 16;              // wave's 16-row group
  const int qoff = (2 * hk + (w >> 2)) * 128; // wave's q-head
  const int kvoff = hk * 128;
  const float qscale = 0.08838834764831845f;  // 1/sqrt(128), folded into Q
  char* Pw = smem + 65536 + w * 2048;         // 16 rows x 128 B per wave

  // ---- Q fragment + RoPE + scale in-register (one 16-row subtile) ----
  bf16x8 aq[4];
  {
    const int l = q0 + wrow + l16;
    const size_t qbase = (size_t)l * 4096 + qoff + quad * 8;
    bf16x8 raw[4];
#pragma unroll
    for (int ks = 0; ks < 4; ++ks)
      raw[ks] = *(const bf16x8*)&Qb[qbase + ks * 32];
#pragma unroll
    for (int ks = 0; ks < 4; ++ks) {
      const float* cp = &cosT[l * 128 + ks * 32 + quad * 8];
      const float* sp = &sinT[l * 128 + ks * 32 + quad * 8];
#pragma unroll
      for (int j = 0; j < 8; ++j) {
        const float cv = cp[j];
        const float sv = sp[j];
        const float rot = (ks < 2) ? -(float)raw[ks + 2][j] : (float)raw[ks - 2][j];
        aq[ks][j] = (__bf16)(((float)raw[ks][j] * cv + rot * sv) * qscale);
      }
    }
  }

  // ---- staging helper: 4 global_load_lds per wave into chosen buffer ----
  auto stage = [&](int kt_, char* buf) {
    const int k0_ = kt_ * 64;
    __bf16* Ksb = (__bf16*)buf;
    __bf16* Vsb = (__bf16*)(buf + 16384);
#pragma unroll
    for (int d = 0; d < 2; ++d) {
      const int r0 = w * 8 + d * 4;              // 4 K-rows per DMA
      const int row = r0 + (lane >> 4);
      const int ck = (lane & 15) ^ (row & 15);
      const __bf16* ga = Kb + (size_t)(k0_ + row) * 2048 + kvoff + ck * 8;
      __builtin_amdgcn_global_load_lds(
          (const __attribute__((address_space(1))) void*)ga,
          (__attribute__((address_space(3))) void*)&Ksb[r0 * 128], 16, 0, 0);
      const int r0v = w * 16 + d * 8;            // 8 V-rows per DMA
      const int rowv = r0v + (lane >> 3);
      const int cv = (lane & 7) ^ (rowv & 7);
      const __bf16* gv = Vt + (size_t)(kvoff + rowv) * 2048 + k0_ + cv * 8;
      __builtin_amdgcn_global_load_lds(
          (const __attribute__((address_space(1))) void*)gv,
          (__attribute__((address_space(3))) void*)&Vsb[r0v * 64], 16, 0, 0);
    }
  };

  f32x4 o[8];
#pragma unroll
  for (int i = 0; i < 8; ++i) o[i] = (f32x4){0.f, 0.f, 0.f, 0.f};
  float m = -1e30f, lsum = 0.f;

  // Drain Q/rope loads so vmcnt counts only staging traffic, then prologue.
  asm volatile("s_waitcnt vmcnt(0)" ::: "memory");
  stage(0, smem);

  for (int kt = 0; kt <= qt; ++kt) {
    const int cur = kt & 1;
    __bf16* Ks = (__bf16*)(smem + cur * 32768);
    __bf16* Vs = (__bf16*)(smem + cur * 32768 + 16384);
    const int k0 = kt * 64;
    if (kt < qt) {
      stage(kt + 1, smem + (cur ^ 1) * 32768);
      asm volatile("s_waitcnt vmcnt(4)" ::: "memory");  // kt's 4 loads done
    } else {
      asm volatile("s_waitcnt vmcnt(0)" ::: "memory");
    }
    __builtin_amdgcn_s_barrier();        // all waves' kt tiles staged
    asm volatile("" ::: "memory");       // pin LDS reads below the barrier
    // ---- S^T = K Q^T : 4 key m-tiles x 4 k-steps ----
    f32x4 st[4];
#pragma unroll
    for (int t = 0; t < 4; ++t) st[t] = (f32x4){0.f, 0.f, 0.f, 0.f};
    __builtin_amdgcn_s_setprio(1);
#pragma unroll
    for (int ks = 0; ks < 4; ++ks) {
#pragma unroll
      for (int t = 0; t < 4; ++t) {
        bf16x8 ak = *(bf16x8*)&Ks[(t * 16 + l16) * 128 + (((ks * 4 + quad) ^ l16) << 3)];
        st[t] = __builtin_amdgcn_mfma_f32_16x16x32_bf16(ak, aq[ks], st[t], 0, 0, 0);
      }
    }
    __builtin_amdgcn_s_setprio(0);
    // ---- online softmax (scale pre-folded into Q) ----
    {
      const int q = q0 + wrow + l16;
      float rm = -1e30f;
      if (kt != qt) {
#pragma unroll
        for (int t = 0; t < 4; ++t)
#pragma unroll
          for (int r = 0; r < 4; ++r) rm = fmaxf(rm, st[t][r]);
      } else {
#pragma unroll
        for (int t = 0; t < 4; ++t)
#pragma unroll
          for (int r = 0; r < 4; ++r) {
            const int key = k0 + t * 16 + quad * 4 + r;
            if (key > q) st[t][r] = -1e30f;
            rm = fmaxf(rm, st[t][r]);
          }
      }
      rm = fmaxf(rm, __shfl_xor(rm, 16, 64));
      rm = fmaxf(rm, __shfl_xor(rm, 32, 64));
      const float mn = fmaxf(m, rm);
      float rs = 0.f;
#pragma unroll
      for (int t = 0; t < 4; ++t)
#pragma unroll
        for (int r = 0; r < 4; ++r) {
          st[t][r] = __expf(st[t][r] - mn);
          rs += st[t][r];
        }
      rs += __shfl_xor(rs, 16, 64);
      rs += __shfl_xor(rs, 32, 64);
      if (__any(rm > m)) {               // max grew: rescale O (exact: else
        const float alpha = __expf(m - mn);  // alpha==exp(0)==1, skip is
        lsum = lsum * alpha + rs;            // bit-identical)
        m = mn;
#pragma unroll
        for (int r = 0; r < 4; ++r) {
          const float ar = __shfl(alpha, quad * 4 + r, 64);
#pragma unroll
          for (int nt = 0; nt < 8; ++nt) o[nt][r] *= ar;
        }
      } else {
        lsum += rs;
      }
      const int prow = l16;
#pragma unroll
      for (int t = 0; t < 4; ++t) {
        bf16x4 pk = {(__bf16)st[t][0], (__bf16)st[t][1],
                     (__bf16)st[t][2], (__bf16)st[t][3]};
        const int wch = (t * 2 + (quad >> 1)) ^ (prow & 7);  // 16B-chunk swizzle
        *(bf16x4*)(Pw + prow * 128 + wch * 16 + (quad & 1) * 8) = pk;
      }
    }
    // ---- O += P V : per-wave P (no barrier) ----
    __builtin_amdgcn_s_setprio(1);
#pragma unroll
    for (int ks = 0; ks < 2; ++ks) {
      const int rch = ((ks * 4 + quad) ^ (l16 & 7)) << 4;   // swizzled 16B chunk
      bf16x8 pa = *(bf16x8*)(Pw + l16 * 128 + rch);
#pragma unroll
      for (int nt = 0; nt < 8; ++nt) {
        bf16x8 bv = *(bf16x8*)&Vs[(nt * 16 + l16) * 64 + (((ks * 4 + quad) ^ (l16 & 7)) << 3)];
        o[nt] = __builtin_amdgcn_mfma_f32_16x16x32_bf16(pa, bv, o[nt], 0, 0, 0);
      }
    }
    __builtin_amdgcn_s_setprio(0);
    // ---- end-of-tile: own LDS reads done, then free buf(kt^1) ----
    asm volatile("s_waitcnt lgkmcnt(0)" ::: "memory");
    __builtin_amdgcn_s_barrier();
    asm volatile("" ::: "memory");
  }
  // ---- epilogue: fused differential combine (loop-end barrier synced all) ----
  const float linv = 1.0f / lsum;
  if (w >= 4) {     // q-head 2hk+1: publish inv-scaled O
#pragma unroll
    for (int r = 0; r < 4; ++r) {
      const float inv = __shfl(linv, quad * 4 + r, 64);
      const int rr = wrow + quad * 4 + r;
#pragma unroll
      for (int nt = 0; nt < 8; ++nt)
        Ex[rr][nt * 16 + l16] = o[nt][r] * inv;
    }
  }
  __syncthreads();
  if (w < 4) {      // q-head 2hk: combine and write y
#pragma unroll
    for (int r = 0; r < 4; ++r) {
      const float inv = __shfl(linv, quad * 4 + r, 64);
      const int rr = wrow + quad * 4 + r;
      const int l = q0 + rr;
      const float lm = lam[l * 16 + hk];
      __bf16* dst = y + (size_t)l * 2048 + hk * 128;
#pragma unroll
      for (int nt = 0; nt < 8; ++nt) {
        const float v1 = o[nt][r] * inv;
        dst[nt * 16 + l16] = (__bf16)(v1 - lm * Ex[rr][nt * 16 + l16]);
      }
    }
  }
}

extern "C" void kernel_launch(void* const* d_in, const int* in_sizes, int n_in,
                              void* d_out, int out_size, void* d_ws, size_t ws_size,
                              hipStream_t stream) {
  const float* x     = (const float*)d_in[0];
  const float* W_DKV = (const float*)d_in[1];
  const float* W_UK  = (const float*)d_in[2];
  const float* W_UV  = (const float*)d_in[3];
  const float* W_DQ  = (const float*)d_in[4];
  const float* W_UQ  = (const float*)d_in[5];
  const float* W_lam = (const float*)d_in[6];
  const float* b_lam = (const float*)d_in[7];
  const float* W_out = (const float*)d_in[8];
  float* out = (float*)d_out;

  char* ws = (char*)d_ws;
  #define MB(n) ((size_t)(n) << 20)
  __bf16* x_bf   = (__bf16*)(ws + MB(0));    //  8 MB (2048x2048)
  __bf16* Wt_DKV = (__bf16*)(ws + MB(8));    //  2 MB (512x2048)
  __bf16* Wt_DQ  = (__bf16*)(ws + MB(10));   //  4 MB (1024x2048)
  __bf16* c_kv   = (__bf16*)(ws + MB(14));   //  2 MB (2048x512)
  __bf16* c_q    = (__bf16*)(ws + MB(16));   //  4 MB (2048x1024)
  __bf16* Wt_UK  = (__bf16*)(ws + MB(20));   //  2 MB (2048x512)
  __bf16* Wt_UV  = (__bf16*)(ws + MB(22));   //  2 MB (2048x512)
  __bf16* Wt_UQ  = (__bf16*)(ws + MB(24));   //  8 MB (4096x1024)
  __bf16* k_bf   = (__bf16*)(ws + MB(32));   //  8 MB (2048x2048)
  __bf16* v_bf   = (__bf16*)(ws + MB(40));   //  8 MB (2048x2048)
  __bf16* y_bf   = (__bf16*)(ws + MB(40));   //  8 MB alias: v_bf dead after v_t
  __bf16* q_bf   = (__bf16*)(ws + MB(48));   // 16 MB (2048x4096) un-roped
  __bf16* v_t    = (__bf16*)(ws + MB(64));   //  8 MB (2048x2048)
  float*  lam    = (float*)(ws + MB(88));    // 128 KB
  float*  cosT   = (float*)(ws + MB(89));    //  1 MB
  float*  sinT   = (float*)(ws + MB(90));    //  1 MB
  __bf16* WlT    = (__bf16*)(ws + MB(91));   // 64 KB (16x2048)
  __bf16* Wt_out = (__bf16*)(ws + MB(92));   //  8 MB (2048x2048)  (total 100 MB)

  // one prep launch: 6 weight transposes + x cast + rope tables + W_lam^T
  prep_all<<<18560, 256, 0, stream>>>(W_DKV, W_DQ, W_UK, W_UV, W_UQ, W_out,
                                      x, W_lam,
                                      Wt_DKV, Wt_DQ, Wt_UK, Wt_UV, Wt_UQ, Wt_out,
                                      x_bf, WlT, cosT, sinT);
  // fused down-projections, BM=64 BK=64 (384 blocks): DKV (4) + DQ (8)
  gemm_fused3<64, 2><<<dim3(12, 32), 256, 0, stream>>>(
      x_bf, Wt_DKV, c_kv, 512, 2048, 4,
      x_bf, Wt_DQ,  c_q, 1024, 2048, 8,
      x_bf, Wt_DQ,  c_q, 1024, 2048);
  lam_mfma_kernel<<<32, 256, 0, stream>>>(x_bf, WlT, b_lam, lam);
  // fused up-projections: UK (16) + UV (16) + UQ (32) — BM=128 BK=32 (4/CU)
  gemm_fused3<128, 1><<<dim3(64, 16), 256, 0, stream>>>(
      c_kv, Wt_UK, k_bf, 2048, 512, 16,
      c_kv, Wt_UV, v_bf, 2048, 512, 16,
      c_q,  Wt_UQ, q_bf, 4096, 1024);
  // K-RoPE + V transpose, one launch
  ropek_transv<<<6144, 256, 0, stream>>>(k_bf, cosT, sinT, v_bf, v_t);
  // flash attention: 8-wave blocks, 4 waves/SIMD pair regime -> y_bf
  attn_kernel3<<<512, 512, 0, stream>>>(q_bf, k_bf, v_t, cosT, sinT, lam, y_bf);
  // output projection, BM=64 BK=64 (512 blocks = 2/CU)
  gemm_mfma<64, 2, false><<<dim3(16, 32), 256, 0, stream>>>(y_bf, Wt_out, out, 2048, 2048, 2048);
}